// Round 9
// baseline (108.450 us; speedup 1.0000x reference)
//
#include <hip/hip_runtime.h>
#include <math.h>

// AFM fused single-pass, 2-row-tile schedule: one block = one sample, 512
// threads (8 waves). A wave owns row-pair (r, r+1); per 16-col tile ONE
// ds_read_b128 of ec feeds TWO mfma_f32_16x16x32_f16 (C=bias), both rows'
// logit partials pack into one f16x2 -> one 2-shfl butterfly for both.
// w = exp2(logit*log2e) (no-max softmax: |logit| < ~0.5), pool in packed f16.
constexpr int kT = 100;
constexpr int kD = 32;
constexpr int kA = 16;
constexpr int kESH = 40;     // e row stride in halfs (80 B)
constexpr int kRows = 116;   // 100 real + 16 zero-pad rows (tail tiles read <= row 112)
constexpr int kNT = 512;     // 8 waves

typedef float    float4v __attribute__((ext_vector_type(4)));
typedef __fp16   fp16x2  __attribute__((ext_vector_type(2)));
typedef __fp16   half4   __attribute__((ext_vector_type(4)));
typedef __fp16   half8   __attribute__((ext_vector_type(8)));
typedef _Float16 half8v  __attribute__((ext_vector_type(8)));

#if __has_builtin(__builtin_amdgcn_exp2f)
#define EXP2F(x) __builtin_amdgcn_exp2f(x)
#else
#define EXP2F(x) exp2f(x)
#endif

// Row-pair i covers rows (2i, 2i+1), cols 2i+1..99, ntiles = ceil((99-2i)/16).
// Static bin-packing of the 50 pairs over 8 waves: 22-23 tiles per wave.
__device__ __constant__ unsigned char kRP[50] = {
    0, 2, 10, 18, 42,            // w0: 7+6+5+4+1 = 23
    1, 3, 11, 19, 43,            // w1: 23
    4, 5, 12, 20, 34,            // w2: 6+6+5+4+2 = 23
    6, 7, 13, 21, 35,            // w3: 23
    8, 14, 22, 26, 27, 36,       // w4: 6+5+4+3+3+2 = 23
    9, 15, 23, 28, 29, 37,       // w5: 23
    16, 17, 24, 30, 31, 38,      // w6: 5+5+4+3+3+2 = 22
    25, 32, 33, 39, 40, 41, 44, 45, 46, 47, 48, 49   // w7: 4+3+3+2+2+2+1*6 = 22
};
__device__ __constant__ unsigned char kRPoff[9] = {0, 5, 10, 15, 20, 26, 32, 38, 50};

// LDS: she = 116 rows * 80 B = 9280 B; stg (512*9 floats = 18432 B) aliases after.
__global__ __launch_bounds__(kNT, 8)
void afm_kernel(const int* __restrict__ x,
                const float* __restrict__ Emb,
                const float* __restrict__ W,    // (32,16)
                const float* __restrict__ bb,   // (16,)
                const float* __restrict__ h,    // (16,)
                const float* __restrict__ W1,   // (32,16)
                const float* __restrict__ b1,   // (16,)
                const float* __restrict__ W2,   // (16,8)
                const float* __restrict__ b2,   // (8,)
                const float* __restrict__ Wf,   // (8,)
                const float* __restrict__ bf,   // (1,)
                float* __restrict__ out)        // (1024,)
{
    __shared__ __align__(16) unsigned char smem[18432];
    __shared__ float red[8];
    __shared__ float sh_pooled[kD];
    __shared__ float sh_o1[kA];
    __shared__ float sh_o2[8];

    __fp16* she = (__fp16*)smem;
    const char* sheb = (const char*)smem;

    const int tid  = threadIdx.x;
    const int b    = blockIdx.x;
    const int lane = tid & 63;
    const int wv   = tid >> 6;           // 0..7
    const int quad = lane >> 4;
    const int l15  = lane & 15;
    const int k0   = quad * 8;           // this quad's K slice (dims k0..k0+7)

    // ---- gather embeddings -> f16 LDS; zero the pad rows ----
    const int* xb = x + b * kT;
    for (int i = tid; i < kT * 8; i += kNT) {
        const int row = i >> 3, c4 = i & 7;
        const int v = xb[row];
        const float4 val = ((const float4*)Emb)[v * 8 + c4];
        union { fp16x2 h2[2]; half4 h4; } tmp;
        tmp.h2[0] = __builtin_amdgcn_cvt_pkrtz(val.x, val.y);
        tmp.h2[1] = __builtin_amdgcn_cvt_pkrtz(val.z, val.w);
        *(half4*)(she + row * kESH + c4 * 4) = tmp.h4;
    }
    if (tid < (kRows - kT) * kESH / 2)   // 320 u32 of zero pad (rows 100..115)
        ((unsigned int*)she)[kT * kESH / 2 + tid] = 0u;

    // ---- A-frag: W^T f16 (lane holds W[k0+j][a=l15]); h*log2e; bias as C ----
    union { fp16x2 h2[4]; half8v h8; } wa;
#pragma unroll
    for (int j = 0; j < 4; ++j)
        wa.h2[j] = __builtin_amdgcn_cvt_pkrtz(W[(k0 + 2 * j) * kA + l15],
                                              W[(k0 + 2 * j + 1) * kA + l15]);
    float h_reg[4];
    float4v bfrag;
#pragma unroll
    for (int rg = 0; rg < 4; ++rg) {
        h_reg[rg] = h[quad * 4 + rg] * 1.44269504088896340736f;  // fold log2(e)
        bfrag[rg] = bb[quad * 4 + rg];
    }
    const int lane_base = l15 * 80 + quad * 16;   // byte offset for ec
    __syncthreads();

    // ---- fused main loop over row-pairs ----
    fp16x2 pool2[4];
    const fp16x2 zz = {(__fp16)0.0f, (__fp16)0.0f};
#pragma unroll
    for (int j = 0; j < 4; ++j) pool2[j] = zz;
    float lsum = 0.0f;

    union HB { half8 fp; fp16x2 h2[4]; half8v mf; };

    auto do_tile = [&](const half8& er1, const half8& er2, int coff,
                       bool first, int rem) {
        HB hb1, hb2;
        const half8 ec = *(const half8*)(sheb + coff);   // ONE read, two rows
        hb1.fp = er1 * ec;                               // 4x v_pk_mul_f16
        hb2.fp = er2 * ec;
        float4v s1 = __builtin_amdgcn_mfma_f32_16x16x32_f16(wa.h8, hb1.mf, bfrag, 0, 0, 0);
        float4v s2 = __builtin_amdgcn_mfma_f32_16x16x32_f16(wa.h8, hb2.mf, bfrag, 0, 0, 0);
        float p1 = 0.0f, p2 = 0.0f;
#pragma unroll
        for (int rg = 0; rg < 4; ++rg) {
            p1 = fmaf(fmaxf(s1[rg], 0.0f), h_reg[rg], p1);
            p2 = fmaf(fmaxf(s2[rg], 0.0f), h_reg[rg], p2);
        }
        union { fp16x2 hh; int ii; } t0, t1;          // packed butterfly, both rows
        t0.hh = __builtin_amdgcn_cvt_pkrtz(p1, p2);
        t1.ii = __shfl_xor(t0.ii, 16, 64);
        t0.hh = t0.hh + t1.hh;
        t1.ii = __shfl_xor(t0.ii, 32, 64);
        t0.hh = t0.hh + t1.hh;
        float w1 = EXP2F((float)t0.hh[0]);
        float w2 = EXP2F((float)t0.hh[1]);
        if (first) w2 = (l15 > 0) ? w2 : 0.0f;        // row2: col must exceed r2
        if (rem < 16) {                                // tail tile only
            const bool v = l15 < rem;
            w1 = v ? w1 : 0.0f;
            w2 = v ? w2 : 0.0f;
        }
        lsum += w1 + w2;
        const fp16x2 ww1 = __builtin_amdgcn_cvt_pkrtz(w1, w1);
        const fp16x2 ww2 = __builtin_amdgcn_cvt_pkrtz(w2, w2);
#pragma unroll
        for (int j = 0; j < 4; ++j) pool2[j] += ww1 * hb1.h2[j];   // v_pk_fma_f16
#pragma unroll
        for (int j = 0; j < 4; ++j) pool2[j] += ww2 * hb2.h2[j];
    };

    const int beg = kRPoff[wv], fin = kRPoff[wv + 1];
    for (int ii = beg; ii < fin; ++ii) {
        const int r1 = 2 * (int)kRP[ii];
        const int len = 99 - r1;                       // cols r1+1..99
        const int ntiles = (len + 15) >> 4;
        const half8 er1 = *(const half8*)(sheb + r1 * 80 + quad * 16);
        const half8 er2 = *(const half8*)(sheb + r1 * 80 + 80 + quad * 16);
        int coff = (r1 + 1) * 80 + lane_base;
        do_tile(er1, er2, coff, true, ntiles == 1 ? len : 99);
        coff += 1280;
        for (int j = 1; j < ntiles - 1; ++j, coff += 1280)
            do_tile(er1, er2, coff, false, 99);
        if (ntiles > 1)
            do_tile(er1, er2, coff, false, len - ((ntiles - 1) << 4));
    }

    // ---- reduce lsum (each pair counted by all 4 quads -> x4) ----
#pragma unroll
    for (int off = 1; off < 64; off <<= 1) lsum += __shfl_xor(lsum, off, 64);
    if (lane == 0) red[wv] = lsum;

    __syncthreads();                 // she reads done; smem reusable
    float* stg = (float*)smem;       // 512 * 9 floats = 18432 B
#pragma unroll
    for (int j = 0; j < 4; ++j) {
        stg[tid * 9 + 2 * j]     = (float)pool2[j][0];
        stg[tid * 9 + 2 * j + 1] = (float)pool2[j][1];
    }
    __syncthreads();

    // pooled[d]: contributors are lanes whose quad == d>>3, all 8 waves
    if (tid < kD) {
        const float invS = 4.0f / (red[0] + red[1] + red[2] + red[3] +
                                   red[4] + red[5] + red[6] + red[7]);
        const int q = tid >> 3, j = tid & 7;
        float s = 0.0f;
        for (int w8 = 0; w8 < 8; ++w8)
            for (int l = 0; l < 16; ++l)
                s += stg[(w8 * 64 + q * 16 + l) * 9 + j];
        sh_pooled[tid] = s * invS;
    }
    __syncthreads();

    // ---- MLP head ----
    if (tid < kA) {
        float o = b1[tid];
#pragma unroll
        for (int d = 0; d < kD; ++d) o = fmaf(sh_pooled[d], W1[d * kA + tid], o);
        sh_o1[tid] = fmaxf(o, 0.0f);
    }
    __syncthreads();
    if (tid < 8) {
        float o = b2[tid];
#pragma unroll
        for (int a = 0; a < kA; ++a) o = fmaf(sh_o1[a], W2[a * 8 + tid], o);
        sh_o2[tid] = fmaxf(o, 0.0f);
    }
    __syncthreads();
    if (tid == 0) {
        float z = bf[0];
#pragma unroll
        for (int j = 0; j < 8; ++j) z = fmaf(sh_o2[j], Wf[j], z);
        out[b] = 1.0f / (1.0f + __expf(-z));
    }
}

extern "C" void kernel_launch(void* const* d_in, const int* in_sizes, int n_in,
                              void* d_out, int out_size, void* d_ws, size_t ws_size,
                              hipStream_t stream) {
    const int*   x   = (const int*)d_in[0];
    const float* Emb = (const float*)d_in[1];
    const float* W   = (const float*)d_in[2];
    const float* bb  = (const float*)d_in[3];
    const float* h   = (const float*)d_in[4];
    const float* W1  = (const float*)d_in[5];
    const float* b1  = (const float*)d_in[6];
    const float* W2  = (const float*)d_in[7];
    const float* b2  = (const float*)d_in[8];
    const float* Wf  = (const float*)d_in[9];
    const float* bf  = (const float*)d_in[10];
    float* out = (float*)d_out;

    afm_kernel<<<1024, kNT, 0, stream>>>(x, Emb, W, bb, h, W1, b1, W2, b2, Wf, bf, out);
}